// Round 16
// baseline (15.607 us; speedup 1.0000x reference)
//
#include <hip/hip_runtime.h>
#include <math.h>

// NUFFT type-2 exact NUDFT via MFMA, LDS-resident B.
// R16 = R15 (verified, 12.56us) + Gauss 3-MFMA complex multiply:
//   P1 += Ar*Br ; P2 += Ai*Bi ; P3 += (Ar+Ai)*(Br+Bi)
//   tmp_re = P1-P2 ; tmp_im = P3-P1-P2      (epilogue fixup, fp32)
// MFMA count 128->96 per wave; LDS reads unchanged; +1 half8 add per (a,kk).
// Everything else byte-identical to R15.

using fp16x2 = __fp16 __attribute__((ext_vector_type(2)));
using half8  = __attribute__((ext_vector_type(8))) _Float16;
using f32x4  = __attribute__((ext_vector_type(4))) float;

constexpr int Bn = 2, Cn = 8, Kn = 2048, Hn = 128, Wn = 128;
constexpr int BC  = Bn * Cn;       // 16
constexpr int KPW = 16;            // k's per wave (one MFMA M-tile)
constexpr int WPB = 8;             // waves per block
constexpr int KPB = KPW * WPB;     // 128 k's per block
constexpr int NKS = Hn / 32;       // 4 K-steps over y
constexpr int SLOTS = Hn * Wn / 8; // 2048 half8 slots per component (32KB)

__device__ inline void cmul(float& ar, float& ai, float br, float bi) {
    float nr = fmaf(ar, br, -ai * bi);
    ai = fmaf(ar, bi, ai * br);
    ar = nr;
}
__device__ inline void csq(float& r, float& i) {
    float nr = fmaf(r, r, -i * i);
    i = 2.f * r * i;
    r = nr;
}

template<int OUT_COMPLEX>
__global__ __launch_bounds__(512, 2)
void nufft_mfma(const float* __restrict__ img_re, const float* __restrict__ img_im,
                const float* __restrict__ traj, float* __restrict__ out)
{
    __shared__ half8 re_lds[SLOTS];   // 32KB (full 128-row image, f16)
    __shared__ half8 im_lds[SLOTS];   // 32KB

    const int bc   = blockIdx.x / (Kn / KPB);   // 0..15
    const int kt   = blockIdx.x % (Kn / KPB);   // 0..15
    const int lane = threadIdx.x & 63;
    const int wave = threadIdx.x >> 6;          // 0..7
    const int xlo  = lane & 15;                 // n-lane (x within tile) / A k-row lane
    const int grp  = lane >> 4;                 // k-slot group (y-offset group)
    const int kbase = kt * KPB + wave * KPW;
    const size_t ibase = (size_t)bc * Hn * Wn;

    // ---- stage the FULL image, fp32 -> f16 (packed rtz) + XOR-swizzle:
    //      slot s holds (x = s>>4, y-chunk j = (s&15)^(x&7))  [R4-verified layout] ----
    #pragma unroll
    for (int i = 0; i < 4; ++i) {
        const int s  = i * 512 + (int)threadIdx.x;   // 0..2047
        const int x  = s >> 4;
        const int j  = (s & 15) ^ (x & 7);
        const float* gr = img_re + ibase + (size_t)x * Wn + j * 8;
        const float* gi = img_im + ibase + (size_t)x * Wn + j * 8;
        float4 a = ((const float4*)gr)[0], b = ((const float4*)gr)[1];
        float4 d = ((const float4*)gi)[0], e = ((const float4*)gi)[1];
        union { fp16x2 v2[4]; half8 v8; } ur, ui;
        ur.v2[0] = __builtin_amdgcn_cvt_pkrtz(a.x, a.y);
        ur.v2[1] = __builtin_amdgcn_cvt_pkrtz(a.z, a.w);
        ur.v2[2] = __builtin_amdgcn_cvt_pkrtz(b.x, b.y);
        ur.v2[3] = __builtin_amdgcn_cvt_pkrtz(b.z, b.w);
        ui.v2[0] = __builtin_amdgcn_cvt_pkrtz(d.x, d.y);
        ui.v2[1] = __builtin_amdgcn_cvt_pkrtz(d.z, d.w);
        ui.v2[2] = __builtin_amdgcn_cvt_pkrtz(e.x, e.y);
        ui.v2[3] = __builtin_amdgcn_cvt_pkrtz(e.z, e.w);
        re_lds[s] = ur.v8;
        im_lds[s] = ui.v8;
    }

    // ---- A (py) fragments, built ONCE (verified math), in the staging shadow ----
    const float om_y = traj[(size_t)(bc * 2 + 1) * Kn + (kbase + xlo)];
    float s, c;
    sincosf(om_y, &s, &c);
    const float syr = c, syi = -s;                    // exp(-i*om_y)
    sincosf(om_y * (float)(grp * 8 - 64), &s, &c);
    float pr = c, pi = -s;                            // phase at y = grp*8
    float t32r = syr, t32i = syi;                     // s_y^32
    #pragma unroll
    for (int q = 0; q < 5; ++q) csq(t32r, t32i);

    half8 Ar[NKS], Ai8[NKS], As[NKS];                 // As = Ar + Ai (Gauss)
    #pragma unroll
    for (int kk = 0; kk < NKS; ++kk) {
        float vr[8], vi[8];
        vr[0] = pr; vi[0] = pi;
        #pragma unroll
        for (int j = 1; j < 8; ++j) {
            float nr = fmaf(vr[j-1], syr, -vi[j-1] * syi);
            vi[j]    = fmaf(vr[j-1], syi,  vi[j-1] * syr);
            vr[j]    = nr;
        }
        #pragma unroll
        for (int j = 0; j < 8; ++j) {
            Ar[kk][j]  = (_Float16)vr[j];
            Ai8[kk][j] = (_Float16)vi[j];
            As[kk][j]  = (_Float16)(vr[j] + vi[j]);
        }
        cmul(pr, pi, t32r, t32i);
    }

    // ---- epilogue px phase constants, hoisted (verified math) ----
    float eqr[4], eqi[4], etr[4], eti[4];
    #pragma unroll
    for (int r = 0; r < 4; ++r) {
        const int kr = kbase + grp * 4 + r;
        const float om_x = traj[(size_t)(bc * 2 + 0) * Kn + kr];
        sincosf(om_x, &s, &c);
        float t16r = c, t16i = -s;                    // exp(-i*om_x)
        sincosf(om_x * (float)(xlo - 64), &s, &c);
        eqr[r] = c; eqi[r] = -s;                      // phase at x = xlo
        #pragma unroll
        for (int q = 0; q < 4; ++q) csq(t16r, t16i);  // s_x^16
        etr[r] = t16r; eti[r] = t16i;
    }

    f32x4 accP1[8], accP2[8], accP3[8];
    #pragma unroll
    for (int a = 0; a < 8; ++a) {
        accP1[a] = (f32x4)0.f; accP2[a] = (f32x4)0.f; accP3[a] = (f32x4)0.f;
    }

    __syncthreads();   // staging complete (the only barrier)

    // ---- MFMA core (R4-verified indexing; Gauss 3-MFMA per (a,kk)) ----
    for (int kk = 0; kk < NKS; ++kk) {
        const int jx = (kk * 4 + grp) ^ (xlo & 7);
        #pragma unroll
        for (int a = 0; a < 8; ++a) {
            const int slot = (a * 16 + xlo) * 16 + jx;
            half8 br = re_lds[slot];
            half8 bi = im_lds[slot];
            half8 bs = br + bi;   // 4x v_pk_add_f16
            accP1[a] = __builtin_amdgcn_mfma_f32_16x16x32_f16(Ar[kk],  br, accP1[a], 0, 0, 0);
            accP2[a] = __builtin_amdgcn_mfma_f32_16x16x32_f16(Ai8[kk], bi, accP2[a], 0, 0, 0);
            accP3[a] = __builtin_amdgcn_mfma_f32_16x16x32_f16(As[kk],  bs, accP3[a], 0, 0, 0);
        }
    }

    // ---- epilogue (verified): out[k] = sum_x tmp[k,x]*px[k,x] ----
    // tmp_re = P1-P2 ; tmp_im = P3-P1-P2
    float outr[4], outi[4];
    #pragma unroll
    for (int r = 0; r < 4; ++r) {
        float qr = eqr[r], qi = eqi[r];
        const float t16r = etr[r], t16i = eti[r];
        float orr = 0.f, oii = 0.f;
        #pragma unroll
        for (int a = 0; a < 8; ++a) {
            const float p1 = accP1[a][r], p2 = accP2[a][r], p3 = accP3[a][r];
            const float tre = p1 - p2;
            const float tim = p3 - p1 - p2;
            orr = fmaf(tre, qr, orr); orr = fmaf(-tim, qi, orr);
            oii = fmaf(tre, qi, oii); oii = fmaf( tim, qr, oii);
            cmul(qr, qi, t16r, t16i);
        }
        #pragma unroll
        for (int m = 1; m < 16; m <<= 1) {
            orr += __shfl_xor(orr, m, 64);
            oii += __shfl_xor(oii, m, 64);
        }
        outr[r] = orr; outi[r] = oii;
    }

    if (xlo == 0) {
        #pragma unroll
        for (int r = 0; r < 4; ++r) {
            const int kr = kbase + grp * 4 + r;
            if (OUT_COMPLEX) {
                out[((size_t)bc * Kn + kr) * 2 + 0] = outr[r];
                out[((size_t)bc * Kn + kr) * 2 + 1] = outi[r];
            } else {
                out[(size_t)bc * Kn + kr] = outr[r];
            }
        }
    }
}

extern "C" void kernel_launch(void* const* d_in, const int* in_sizes, int n_in,
                              void* d_out, int out_size, void* d_ws, size_t ws_size,
                              hipStream_t stream) {
    const float* img_re = (const float*)d_in[0];
    const float* img_im = (const float*)d_in[1];
    const float* traj   = (const float*)d_in[2];
    float* out = (float*)d_out;

    dim3 grid(BC * (Kn / KPB));   // 256 blocks
    dim3 block(WPB * 64);         // 512 threads = 8 waves
    const bool cplx = (out_size == BC * Kn * 2);

    if (cplx) hipLaunchKernelGGL((nufft_mfma<1>), grid, block, 0, stream, img_re, img_im, traj, out);
    else      hipLaunchKernelGGL((nufft_mfma<0>), grid, block, 0, stream, img_re, img_im, traj, out);
}

// Round 17
// 12.048 us; speedup vs baseline: 1.2954x; 1.2954x over previous
//
#include <hip/hip_runtime.h>
#include <math.h>

// NUFFT type-2 exact NUDFT via MFMA, LDS-resident B.
// R18 = R15 (verified best, 12.56us; Gauss R16 reverted) + s_setprio(1) around
// the MFMA cluster (T5: waves are phase-diverse after the single barrier).
//   tmp[k,x] = sum_y py[k,y]*img[x,y]  (f16 MFMA, fp32 acc)
//   out[k]   = sum_x tmp[k,x]*px[k,x]  (VALU epilogue, 16-lane butterfly, direct store)

using fp16x2 = __fp16 __attribute__((ext_vector_type(2)));
using half8  = __attribute__((ext_vector_type(8))) _Float16;
using f32x4  = __attribute__((ext_vector_type(4))) float;

constexpr int Bn = 2, Cn = 8, Kn = 2048, Hn = 128, Wn = 128;
constexpr int BC  = Bn * Cn;       // 16
constexpr int KPW = 16;            // k's per wave (one MFMA M-tile)
constexpr int WPB = 8;             // waves per block
constexpr int KPB = KPW * WPB;     // 128 k's per block
constexpr int NKS = Hn / 32;       // 4 K-steps over y
constexpr int SLOTS = Hn * Wn / 8; // 2048 half8 slots per component (32KB)

__device__ inline void cmul(float& ar, float& ai, float br, float bi) {
    float nr = fmaf(ar, br, -ai * bi);
    ai = fmaf(ar, bi, ai * br);
    ar = nr;
}
__device__ inline void csq(float& r, float& i) {
    float nr = fmaf(r, r, -i * i);
    i = 2.f * r * i;
    r = nr;
}

template<int OUT_COMPLEX>
__global__ __launch_bounds__(512, 2)
void nufft_mfma(const float* __restrict__ img_re, const float* __restrict__ img_im,
                const float* __restrict__ traj, float* __restrict__ out)
{
    __shared__ half8 re_lds[SLOTS];   // 32KB (full 128-row image, f16)
    __shared__ half8 im_lds[SLOTS];   // 32KB

    const int bc   = blockIdx.x / (Kn / KPB);   // 0..15
    const int kt   = blockIdx.x % (Kn / KPB);   // 0..15
    const int lane = threadIdx.x & 63;
    const int wave = threadIdx.x >> 6;          // 0..7
    const int xlo  = lane & 15;                 // n-lane (x within tile) / A k-row lane
    const int grp  = lane >> 4;                 // k-slot group (y-offset group)
    const int kbase = kt * KPB + wave * KPW;
    const size_t ibase = (size_t)bc * Hn * Wn;

    // ---- stage the FULL image, fp32 -> f16 (packed rtz) + XOR-swizzle:
    //      slot s holds (x = s>>4, y-chunk j = (s&15)^(x&7))  [R4-verified layout] ----
    #pragma unroll
    for (int i = 0; i < 4; ++i) {
        const int s  = i * 512 + (int)threadIdx.x;   // 0..2047
        const int x  = s >> 4;
        const int j  = (s & 15) ^ (x & 7);
        const float* gr = img_re + ibase + (size_t)x * Wn + j * 8;
        const float* gi = img_im + ibase + (size_t)x * Wn + j * 8;
        float4 a = ((const float4*)gr)[0], b = ((const float4*)gr)[1];
        float4 d = ((const float4*)gi)[0], e = ((const float4*)gi)[1];
        union { fp16x2 v2[4]; half8 v8; } ur, ui;
        ur.v2[0] = __builtin_amdgcn_cvt_pkrtz(a.x, a.y);
        ur.v2[1] = __builtin_amdgcn_cvt_pkrtz(a.z, a.w);
        ur.v2[2] = __builtin_amdgcn_cvt_pkrtz(b.x, b.y);
        ur.v2[3] = __builtin_amdgcn_cvt_pkrtz(b.z, b.w);
        ui.v2[0] = __builtin_amdgcn_cvt_pkrtz(d.x, d.y);
        ui.v2[1] = __builtin_amdgcn_cvt_pkrtz(d.z, d.w);
        ui.v2[2] = __builtin_amdgcn_cvt_pkrtz(e.x, e.y);
        ui.v2[3] = __builtin_amdgcn_cvt_pkrtz(e.z, e.w);
        re_lds[s] = ur.v8;
        im_lds[s] = ui.v8;
    }

    // ---- A (py) fragments, built ONCE (verified math), in the staging shadow ----
    const float om_y = traj[(size_t)(bc * 2 + 1) * Kn + (kbase + xlo)];
    float s, c;
    sincosf(om_y, &s, &c);
    const float syr = c, syi = -s;                    // exp(-i*om_y)
    sincosf(om_y * (float)(grp * 8 - 64), &s, &c);
    float pr = c, pi = -s;                            // phase at y = grp*8
    float t32r = syr, t32i = syi;                     // s_y^32
    #pragma unroll
    for (int q = 0; q < 5; ++q) csq(t32r, t32i);

    half8 Ar[NKS], Ai8[NKS], An[NKS];
    #pragma unroll
    for (int kk = 0; kk < NKS; ++kk) {
        float vr[8], vi[8];
        vr[0] = pr; vi[0] = pi;
        #pragma unroll
        for (int j = 1; j < 8; ++j) {
            float nr = fmaf(vr[j-1], syr, -vi[j-1] * syi);
            vi[j]    = fmaf(vr[j-1], syi,  vi[j-1] * syr);
            vr[j]    = nr;
        }
        #pragma unroll
        for (int j = 0; j < 8; ++j) {
            Ar[kk][j]  = (_Float16)vr[j];
            Ai8[kk][j] = (_Float16)vi[j];
            An[kk][j]  = (_Float16)(-vi[j]);
        }
        cmul(pr, pi, t32r, t32i);
    }

    // ---- epilogue px phase constants, hoisted (verified math) ----
    float eqr[4], eqi[4], etr[4], eti[4];
    #pragma unroll
    for (int r = 0; r < 4; ++r) {
        const int kr = kbase + grp * 4 + r;
        const float om_x = traj[(size_t)(bc * 2 + 0) * Kn + kr];
        sincosf(om_x, &s, &c);
        float t16r = c, t16i = -s;                    // exp(-i*om_x)
        sincosf(om_x * (float)(xlo - 64), &s, &c);
        eqr[r] = c; eqi[r] = -s;                      // phase at x = xlo
        #pragma unroll
        for (int q = 0; q < 4; ++q) csq(t16r, t16i);  // s_x^16
        etr[r] = t16r; eti[r] = t16i;
    }

    f32x4 accr[8], acci[8];
    #pragma unroll
    for (int a = 0; a < 8; ++a) { accr[a] = (f32x4)0.f; acci[a] = (f32x4)0.f; }

    __syncthreads();   // staging complete (the only barrier)

    // ---- MFMA core (R4-verified indexing), priority-boosted (T5) ----
    __builtin_amdgcn_s_setprio(1);
    for (int kk = 0; kk < NKS; ++kk) {
        const int jx = (kk * 4 + grp) ^ (xlo & 7);
        #pragma unroll
        for (int a = 0; a < 8; ++a) {
            const int slot = (a * 16 + xlo) * 16 + jx;
            half8 br = re_lds[slot];
            half8 bi = im_lds[slot];
            accr[a] = __builtin_amdgcn_mfma_f32_16x16x32_f16(Ar[kk],  br, accr[a], 0, 0, 0);
            accr[a] = __builtin_amdgcn_mfma_f32_16x16x32_f16(An[kk],  bi, accr[a], 0, 0, 0);
            acci[a] = __builtin_amdgcn_mfma_f32_16x16x32_f16(Ar[kk],  bi, acci[a], 0, 0, 0);
            acci[a] = __builtin_amdgcn_mfma_f32_16x16x32_f16(Ai8[kk], br, acci[a], 0, 0, 0);
        }
    }
    __builtin_amdgcn_s_setprio(0);

    // ---- epilogue (verified): out[k] = sum_x tmp[k,x]*px[k,x] ----
    float outr[4], outi[4];
    #pragma unroll
    for (int r = 0; r < 4; ++r) {
        float qr = eqr[r], qi = eqi[r];
        const float t16r = etr[r], t16i = eti[r];
        float orr = 0.f, oii = 0.f;
        #pragma unroll
        for (int a = 0; a < 8; ++a) {
            const float tre = accr[a][r], tim = acci[a][r];
            orr = fmaf(tre, qr, orr); orr = fmaf(-tim, qi, orr);
            oii = fmaf(tre, qi, oii); oii = fmaf( tim, qr, oii);
            cmul(qr, qi, t16r, t16i);
        }
        #pragma unroll
        for (int m = 1; m < 16; m <<= 1) {
            orr += __shfl_xor(orr, m, 64);
            oii += __shfl_xor(oii, m, 64);
        }
        outr[r] = orr; outi[r] = oii;
    }

    if (xlo == 0) {
        #pragma unroll
        for (int r = 0; r < 4; ++r) {
            const int kr = kbase + grp * 4 + r;
            if (OUT_COMPLEX) {
                out[((size_t)bc * Kn + kr) * 2 + 0] = outr[r];
                out[((size_t)bc * Kn + kr) * 2 + 1] = outi[r];
            } else {
                out[(size_t)bc * Kn + kr] = outr[r];
            }
        }
    }
}

extern "C" void kernel_launch(void* const* d_in, const int* in_sizes, int n_in,
                              void* d_out, int out_size, void* d_ws, size_t ws_size,
                              hipStream_t stream) {
    const float* img_re = (const float*)d_in[0];
    const float* img_im = (const float*)d_in[1];
    const float* traj   = (const float*)d_in[2];
    float* out = (float*)d_out;

    dim3 grid(BC * (Kn / KPB));   // 256 blocks
    dim3 block(WPB * 64);         // 512 threads = 8 waves
    const bool cplx = (out_size == BC * Kn * 2);

    if (cplx) hipLaunchKernelGGL((nufft_mfma<1>), grid, block, 0, stream, img_re, img_im, traj, out);
    else      hipLaunchKernelGGL((nufft_mfma<0>), grid, block, 0, stream, img_re, img_im, traj, out);
}

// Round 18
// 12.046 us; speedup vs baseline: 1.2956x; 1.0002x over previous
//
#include <hip/hip_runtime.h>
#include <math.h>

// NUFFT type-2 exact NUDFT via MFMA, LDS-resident B.
// R19 = R18 (verified best, 12.05us) + full unroll of the kk loop so the compiler
// can hoist ds_read_b128 across K-steps (counted lgkmcnt overlap under MFMAs).
// Everything else byte-identical to R18.
//   tmp[k,x] = sum_y py[k,y]*img[x,y]  (f16 MFMA, fp32 acc)
//   out[k]   = sum_x tmp[k,x]*px[k,x]  (VALU epilogue, 16-lane butterfly, direct store)

using fp16x2 = __fp16 __attribute__((ext_vector_type(2)));
using half8  = __attribute__((ext_vector_type(8))) _Float16;
using f32x4  = __attribute__((ext_vector_type(4))) float;

constexpr int Bn = 2, Cn = 8, Kn = 2048, Hn = 128, Wn = 128;
constexpr int BC  = Bn * Cn;       // 16
constexpr int KPW = 16;            // k's per wave (one MFMA M-tile)
constexpr int WPB = 8;             // waves per block
constexpr int KPB = KPW * WPB;     // 128 k's per block
constexpr int NKS = Hn / 32;       // 4 K-steps over y
constexpr int SLOTS = Hn * Wn / 8; // 2048 half8 slots per component (32KB)

__device__ inline void cmul(float& ar, float& ai, float br, float bi) {
    float nr = fmaf(ar, br, -ai * bi);
    ai = fmaf(ar, bi, ai * br);
    ar = nr;
}
__device__ inline void csq(float& r, float& i) {
    float nr = fmaf(r, r, -i * i);
    i = 2.f * r * i;
    r = nr;
}

template<int OUT_COMPLEX>
__global__ __launch_bounds__(512, 2)
void nufft_mfma(const float* __restrict__ img_re, const float* __restrict__ img_im,
                const float* __restrict__ traj, float* __restrict__ out)
{
    __shared__ half8 re_lds[SLOTS];   // 32KB (full 128-row image, f16)
    __shared__ half8 im_lds[SLOTS];   // 32KB

    const int bc   = blockIdx.x / (Kn / KPB);   // 0..15
    const int kt   = blockIdx.x % (Kn / KPB);   // 0..15
    const int lane = threadIdx.x & 63;
    const int wave = threadIdx.x >> 6;          // 0..7
    const int xlo  = lane & 15;                 // n-lane (x within tile) / A k-row lane
    const int grp  = lane >> 4;                 // k-slot group (y-offset group)
    const int kbase = kt * KPB + wave * KPW;
    const size_t ibase = (size_t)bc * Hn * Wn;

    // ---- stage the FULL image, fp32 -> f16 (packed rtz) + XOR-swizzle:
    //      slot s holds (x = s>>4, y-chunk j = (s&15)^(x&7))  [R4-verified layout] ----
    #pragma unroll
    for (int i = 0; i < 4; ++i) {
        const int s  = i * 512 + (int)threadIdx.x;   // 0..2047
        const int x  = s >> 4;
        const int j  = (s & 15) ^ (x & 7);
        const float* gr = img_re + ibase + (size_t)x * Wn + j * 8;
        const float* gi = img_im + ibase + (size_t)x * Wn + j * 8;
        float4 a = ((const float4*)gr)[0], b = ((const float4*)gr)[1];
        float4 d = ((const float4*)gi)[0], e = ((const float4*)gi)[1];
        union { fp16x2 v2[4]; half8 v8; } ur, ui;
        ur.v2[0] = __builtin_amdgcn_cvt_pkrtz(a.x, a.y);
        ur.v2[1] = __builtin_amdgcn_cvt_pkrtz(a.z, a.w);
        ur.v2[2] = __builtin_amdgcn_cvt_pkrtz(b.x, b.y);
        ur.v2[3] = __builtin_amdgcn_cvt_pkrtz(b.z, b.w);
        ui.v2[0] = __builtin_amdgcn_cvt_pkrtz(d.x, d.y);
        ui.v2[1] = __builtin_amdgcn_cvt_pkrtz(d.z, d.w);
        ui.v2[2] = __builtin_amdgcn_cvt_pkrtz(e.x, e.y);
        ui.v2[3] = __builtin_amdgcn_cvt_pkrtz(e.z, e.w);
        re_lds[s] = ur.v8;
        im_lds[s] = ui.v8;
    }

    // ---- A (py) fragments, built ONCE (verified math), in the staging shadow ----
    const float om_y = traj[(size_t)(bc * 2 + 1) * Kn + (kbase + xlo)];
    float s, c;
    sincosf(om_y, &s, &c);
    const float syr = c, syi = -s;                    // exp(-i*om_y)
    sincosf(om_y * (float)(grp * 8 - 64), &s, &c);
    float pr = c, pi = -s;                            // phase at y = grp*8
    float t32r = syr, t32i = syi;                     // s_y^32
    #pragma unroll
    for (int q = 0; q < 5; ++q) csq(t32r, t32i);

    half8 Ar[NKS], Ai8[NKS], An[NKS];
    #pragma unroll
    for (int kk = 0; kk < NKS; ++kk) {
        float vr[8], vi[8];
        vr[0] = pr; vi[0] = pi;
        #pragma unroll
        for (int j = 1; j < 8; ++j) {
            float nr = fmaf(vr[j-1], syr, -vi[j-1] * syi);
            vi[j]    = fmaf(vr[j-1], syi,  vi[j-1] * syr);
            vr[j]    = nr;
        }
        #pragma unroll
        for (int j = 0; j < 8; ++j) {
            Ar[kk][j]  = (_Float16)vr[j];
            Ai8[kk][j] = (_Float16)vi[j];
            An[kk][j]  = (_Float16)(-vi[j]);
        }
        cmul(pr, pi, t32r, t32i);
    }

    // ---- epilogue px phase constants, hoisted (verified math) ----
    float eqr[4], eqi[4], etr[4], eti[4];
    #pragma unroll
    for (int r = 0; r < 4; ++r) {
        const int kr = kbase + grp * 4 + r;
        const float om_x = traj[(size_t)(bc * 2 + 0) * Kn + kr];
        sincosf(om_x, &s, &c);
        float t16r = c, t16i = -s;                    // exp(-i*om_x)
        sincosf(om_x * (float)(xlo - 64), &s, &c);
        eqr[r] = c; eqi[r] = -s;                      // phase at x = xlo
        #pragma unroll
        for (int q = 0; q < 4; ++q) csq(t16r, t16i);  // s_x^16
        etr[r] = t16r; eti[r] = t16i;
    }

    f32x4 accr[8], acci[8];
    #pragma unroll
    for (int a = 0; a < 8; ++a) { accr[a] = (f32x4)0.f; acci[a] = (f32x4)0.f; }

    __syncthreads();   // staging complete (the only barrier)

    // ---- MFMA core (R4-verified indexing), priority-boosted, fully unrolled ----
    __builtin_amdgcn_s_setprio(1);
    #pragma unroll
    for (int kk = 0; kk < NKS; ++kk) {
        const int jx = (kk * 4 + grp) ^ (xlo & 7);
        #pragma unroll
        for (int a = 0; a < 8; ++a) {
            const int slot = (a * 16 + xlo) * 16 + jx;
            half8 br = re_lds[slot];
            half8 bi = im_lds[slot];
            accr[a] = __builtin_amdgcn_mfma_f32_16x16x32_f16(Ar[kk],  br, accr[a], 0, 0, 0);
            accr[a] = __builtin_amdgcn_mfma_f32_16x16x32_f16(An[kk],  bi, accr[a], 0, 0, 0);
            acci[a] = __builtin_amdgcn_mfma_f32_16x16x32_f16(Ar[kk],  bi, acci[a], 0, 0, 0);
            acci[a] = __builtin_amdgcn_mfma_f32_16x16x32_f16(Ai8[kk], br, acci[a], 0, 0, 0);
        }
    }
    __builtin_amdgcn_s_setprio(0);

    // ---- epilogue (verified): out[k] = sum_x tmp[k,x]*px[k,x] ----
    float outr[4], outi[4];
    #pragma unroll
    for (int r = 0; r < 4; ++r) {
        float qr = eqr[r], qi = eqi[r];
        const float t16r = etr[r], t16i = eti[r];
        float orr = 0.f, oii = 0.f;
        #pragma unroll
        for (int a = 0; a < 8; ++a) {
            const float tre = accr[a][r], tim = acci[a][r];
            orr = fmaf(tre, qr, orr); orr = fmaf(-tim, qi, orr);
            oii = fmaf(tre, qi, oii); oii = fmaf( tim, qr, oii);
            cmul(qr, qi, t16r, t16i);
        }
        #pragma unroll
        for (int m = 1; m < 16; m <<= 1) {
            orr += __shfl_xor(orr, m, 64);
            oii += __shfl_xor(oii, m, 64);
        }
        outr[r] = orr; outi[r] = oii;
    }

    if (xlo == 0) {
        #pragma unroll
        for (int r = 0; r < 4; ++r) {
            const int kr = kbase + grp * 4 + r;
            if (OUT_COMPLEX) {
                out[((size_t)bc * Kn + kr) * 2 + 0] = outr[r];
                out[((size_t)bc * Kn + kr) * 2 + 1] = outi[r];
            } else {
                out[(size_t)bc * Kn + kr] = outr[r];
            }
        }
    }
}

extern "C" void kernel_launch(void* const* d_in, const int* in_sizes, int n_in,
                              void* d_out, int out_size, void* d_ws, size_t ws_size,
                              hipStream_t stream) {
    const float* img_re = (const float*)d_in[0];
    const float* img_im = (const float*)d_in[1];
    const float* traj   = (const float*)d_in[2];
    float* out = (float*)d_out;

    dim3 grid(BC * (Kn / KPB));   // 256 blocks
    dim3 block(WPB * 64);         // 512 threads = 8 waves
    const bool cplx = (out_size == BC * Kn * 2);

    if (cplx) hipLaunchKernelGGL((nufft_mfma<1>), grid, block, 0, stream, img_re, img_im, traj, out);
    else      hipLaunchKernelGGL((nufft_mfma<0>), grid, block, 0, stream, img_re, img_im, traj, out);
}